// Round 1
// baseline (457.401 us; speedup 1.0000x reference)
//
#include <hip/hip_runtime.h>

constexpr int NB = 16;
constexpr int NCI = 64;
constexpr int NCO = 64;
constexpr int NH = 256;
constexpr int NW = 256;
constexpr int NM1 = 20;
constexpr int NM2 = 20;
constexpr int NMODES = 400;

// workspace layout (float offsets)
constexpr long OFF_TIW = 0;                                  // [40][256] inverse-w table
constexpr long OFF_XL  = 10240;                              // [NB][NCI][400][2]
constexpr long OFF_OL  = OFF_XL + (long)NB*NCI*NMODES*2;     // [NB][NCO][400][2]

constexpr float TWO_PI = 6.28318530717958647692f;

// ---------------- table init: inverse-w table with c_ky and 1/(H*W) folded in ----
__global__ void init_tabs(float* __restrict__ ws) {
    int e = blockIdx.x * 256 + threadIdx.x;
    if (e >= 40 * 256) return;
    int n = e >> 8, w = e & 255;
    int ky = n >> 1, p = n & 1;
    float cky = (ky == 0) ? 1.0f : 2.0f;
    int idx = (ky * w) & 255;
    float ang = TWO_PI * (float)idx * (1.0f / 256.0f);
    float s, c;
    sincosf(ang, &s, &c);
    float v = p ? (-cky * s) : (cky * c);
    ws[OFF_TIW + e] = v * (1.0f / 65536.0f);
}

// ---------------- forward: x -> X_low (fused W-DFT then H-DFT) ------------------
// one block per (b*64+i); 256 threads
__launch_bounds__(256, 2)
__global__ void fwd_kernel(const float* __restrict__ x, float* __restrict__ ws) {
    __shared__ float sm[19072];
    float* sX = sm;              // [32][260] transposed x chunk (8320 floats)
    float* cs = sm + 8320;       // [256][2] cos/sin table (512)
    float* sA = sm + 8832;       // [256][40] A[h][ky complex] (10240)
    const int t = threadIdx.x;
    const int r = blockIdx.x;                 // b*64+i
    const float* xr = x + (long)r * (NH * NW);

    {
        float ang = TWO_PI * (float)t * (1.0f / 256.0f);
        float s, c;
        sincosf(ang, &s, &c);
        cs[2 * t] = c; cs[2 * t + 1] = s;
    }
    __syncthreads();

    const int rg = t >> 2;    // [0,64): 4 h-rows each
    const int cg = t & 3;     // [0,4):  5 complex ky each
    float acc[4][5][2];
#pragma unroll
    for (int a0 = 0; a0 < 4; a0++)
#pragma unroll
        for (int a1 = 0; a1 < 5; a1++) { acc[a0][a1][0] = 0.f; acc[a0][a1][1] = 0.f; }

    for (int kc = 0; kc < 8; ++kc) {
        __syncthreads();
        // stage x chunk transposed: sX[k][h]
#pragma unroll
        for (int j = 0; j < 8; ++j) {
            int e = t + 256 * j;            // [0,2048)
            int h = e >> 3, kq = e & 7;
            float4 g = *(const float4*)(xr + (long)h * NW + kc * 32 + kq * 4);
            sX[(kq * 4 + 0) * 260 + h] = g.x;
            sX[(kq * 4 + 1) * 260 + h] = g.y;
            sX[(kq * 4 + 2) * 260 + h] = g.z;
            sX[(kq * 4 + 3) * 260 + h] = g.w;
        }
        __syncthreads();
        for (int k = 0; k < 32; ++k) {
            int wg = kc * 32 + k;
            float4 xv = *(const float4*)(sX + k * 260 + 4 * rg);
            float xa[4] = {xv.x, xv.y, xv.z, xv.w};
#pragma unroll
            for (int kk = 0; kk < 5; ++kk) {
                int ky = 5 * cg + kk;
                int idx = (ky * wg) & 255;
                float c = cs[2 * idx], s = cs[2 * idx + 1];
#pragma unroll
                for (int rr = 0; rr < 4; ++rr) {
                    acc[rr][kk][0] += xa[rr] * c;   // Re: +x*cos
                    acc[rr][kk][1] -= xa[rr] * s;   // Im: -x*sin   (e^{-i th})
                }
            }
        }
    }
    // write A to LDS
#pragma unroll
    for (int rr = 0; rr < 4; rr++)
#pragma unroll
        for (int kk = 0; kk < 5; kk++) {
            int hh = 4 * rg + rr;
            int ky = 5 * cg + kk;
            sA[hh * 40 + 2 * ky]     = acc[rr][kk][0];
            sA[hh * 40 + 2 * ky + 1] = acc[rr][kk][1];
        }
    __syncthreads();

    // phase 2: X_low[kx,ky] = sum_h A[h][ky] * e^{-2pi i kx h/256}
    float a2[8];
#pragma unroll
    for (int q = 0; q < 8; q++) a2[q] = 0.f;
    if (t < 200) {
        int p = t % 100, sh = t / 100;
        int kxg = p / 10, kyg = p % 10;
        int kx0 = 2 * kxg;
        for (int it = 0; it < 128; ++it) {
            int h = 128 * sh + it;
            float4 a = *(const float4*)(sA + h * 40 + 4 * kyg); // re0,im0,re1,im1
            int i0 = (kx0 * h) & 255;
            int i1 = (i0 + h) & 255;   // (kx0+1)*h mod 256
            float c0 = cs[2 * i0], s0 = cs[2 * i0 + 1];
            float c1 = cs[2 * i1], s1 = cs[2 * i1 + 1];
            // (re + i im)(c - i s) = (re c + im s) + i(im c - re s)
            a2[0] += a.x * c0 + a.y * s0;  a2[1] += a.y * c0 - a.x * s0;
            a2[2] += a.z * c0 + a.w * s0;  a2[3] += a.w * c0 - a.z * s0;
            a2[4] += a.x * c1 + a.y * s1;  a2[5] += a.y * c1 - a.x * s1;
            a2[6] += a.z * c1 + a.w * s1;  a2[7] += a.w * c1 - a.z * s1;
        }
    }
    float* sRed = sX;  // reuse (1600 floats)
    if (t < 200) {
#pragma unroll
        for (int q = 0; q < 8; q++) sRed[t * 8 + q] = a2[q];
    }
    __syncthreads();
    if (t < 100) {
        int kxg = t / 10, kyg = t % 10;
        float* xl = ws + OFF_XL + (long)r * (NMODES * 2);
#pragma unroll
        for (int kxi = 0; kxi < 2; kxi++)
#pragma unroll
            for (int kyi = 0; kyi < 2; kyi++) {
                int q = kxi * 4 + kyi * 2;
                float re = sRed[t * 8 + q]     + sRed[(t + 100) * 8 + q];
                float im = sRed[t * 8 + q + 1] + sRed[(t + 100) * 8 + q + 1];
                int m = (2 * kxg + kxi) * NM2 + (2 * kyg + kyi);
                xl[2 * m]     = re;
                xl[2 * m + 1] = im;
            }
    }
}

// ---------------- channel mix: OL[b,o,m] = sum_i X[b,i,m]*W[i,o,m] --------------
// grid 1024: (o, mq, bq); 256 threads
__launch_bounds__(256, 4)
__global__ void mix_kernel(const float* __restrict__ wre, const float* __restrict__ wim,
                           float* __restrict__ ws) {
    __shared__ float sw[200];   // w re[100] | im[100] for current i
    __shared__ float sx[800];   // X[4 b][100 m][2] for current i
    const int t = threadIdx.x;
    const int blk = blockIdx.x;
    const int o  = blk >> 4;
    const int mq = (blk >> 2) & 3;
    const int bq = blk & 3;
    const int m0 = mq * 100;
    const float* XL = ws + OFF_XL;
    float acc[2][2];
    acc[0][0] = acc[0][1] = acc[1][0] = acc[1][1] = 0.f;
    for (int i = 0; i < NCI; ++i) {
        __syncthreads();
        if (t < 100)      sw[t] = wre[(long)(i * NCO + o) * NMODES + m0 + t];
        else if (t < 200) sw[t] = wim[(long)(i * NCO + o) * NMODES + m0 + (t - 100)];
#pragma unroll
        for (int j = 0; j < 4; ++j) {
            int u = t + 256 * j;
            if (u < 800) {
                int bl = u / 200, q = u % 200;
                int b = 4 * bq + bl;
                sx[u] = XL[((long)(b * NCI + i) * NMODES + m0) * 2 + q];
            }
        }
        __syncthreads();
#pragma unroll
        for (int j = 0; j < 2; ++j) {
            int v = t + 256 * j;
            if (v < 400) {
                int bl = v / 100, ml = v % 100;
                float xr = sx[bl * 200 + 2 * ml], xi = sx[bl * 200 + 2 * ml + 1];
                float wr = sw[ml], wi = sw[100 + ml];
                acc[j][0] += xr * wr - xi * wi;
                acc[j][1] += xr * wi + xi * wr;
            }
        }
    }
    float* OL = ws + OFF_OL;
#pragma unroll
    for (int j = 0; j < 2; ++j) {
        int v = t + 256 * j;
        if (v < 400) {
            int bl = v / 100, ml = v % 100;
            int b = 4 * bq + bl;
            long a = ((long)(b * NCO + o) * NMODES + m0 + ml) * 2;
            OL[a]     = acc[j][0];
            OL[a + 1] = acc[j][1];
        }
    }
}

// ---------------- inverse: OL -> out (fused H-iDFT then W-iDFT) -----------------
// grid 4096: (bo, hq); 256 threads
__launch_bounds__(256, 2)
__global__ void inv_kernel(const float* __restrict__ ws, float* __restrict__ out) {
    __shared__ float sm2[14112];
    float* sOL = sm2;            // 800
    float* cs  = sm2 + 800;      // 512
    float* sY  = sm2 + 1312;     // [40][64]  (2560)
    float* sT2 = sm2 + 3872;     // [40][256] (10240)
    const int t = threadIdx.x;
    const int blk = blockIdx.x;
    const int bo = blk >> 2;     // b*64+o
    const int hq = blk & 3;
    {
        float ang = TWO_PI * (float)t * (1.0f / 256.0f);
        float s, c;
        sincosf(ang, &s, &c);
        cs[2 * t] = c; cs[2 * t + 1] = s;
    }
    {
        const float* OL = ws + OFF_OL + (long)bo * (NMODES * 2);
#pragma unroll
        for (int j = 0; j < 4; ++j) {
            int u = t + 256 * j;
            if (u < 800) sOL[u] = OL[u];
        }
        const float* T2 = ws + OFF_TIW;
#pragma unroll
        for (int j = 0; j < 10; ++j) {
            int u4 = (t + 256 * j) * 4;
            *(float4*)(sT2 + u4) = *(const float4*)(T2 + u4);
        }
    }
    __syncthreads();
    // phase 1: Y2t[2ky+{0,1}][hloc] = H-iDFT of OL (e^{+i th})
    {
        int hloc = t >> 2, kyq = t & 3;
        int h = hq * 64 + hloc;
        float a[5][2];
#pragma unroll
        for (int kk = 0; kk < 5; kk++) { a[kk][0] = 0.f; a[kk][1] = 0.f; }
        for (int kx = 0; kx < NM1; ++kx) {
            int idx = (kx * h) & 255;
            float c = cs[2 * idx], s = cs[2 * idx + 1];
#pragma unroll
            for (int kk = 0; kk < 5; ++kk) {
                int ky = kyq * 5 + kk;
                float pr = sOL[2 * (kx * NM2 + ky)], pi = sOL[2 * (kx * NM2 + ky) + 1];
                a[kk][0] += pr * c - pi * s;
                a[kk][1] += pr * s + pi * c;
            }
        }
#pragma unroll
        for (int kk = 0; kk < 5; ++kk) {
            int ky = kyq * 5 + kk;
            sY[(2 * ky) * 64 + hloc]     = a[kk][0];
            sY[(2 * ky + 1) * 64 + hloc] = a[kk][1];
        }
    }
    __syncthreads();
    // phase 2: out[h][w] = sum_n Y2t[n][h] * T2[n][w]
    {
        const int rg = t >> 4;
        const int wg = t & 15;
        const int w0 = wg * 16;
        float acc[4][16];
#pragma unroll
        for (int rr = 0; rr < 4; rr++)
#pragma unroll
            for (int cc = 0; cc < 16; cc++) acc[rr][cc] = 0.f;
        for (int k = 0; k < 40; ++k) {
            float4 yv = *(const float4*)(sY + k * 64 + 4 * rg);
            float ya[4] = {yv.x, yv.y, yv.z, yv.w};
            float tv[16];
#pragma unroll
            for (int c4 = 0; c4 < 4; ++c4) {
                float4 tt = *(const float4*)(sT2 + k * 256 + w0 + 4 * c4);
                tv[4 * c4 + 0] = tt.x; tv[4 * c4 + 1] = tt.y;
                tv[4 * c4 + 2] = tt.z; tv[4 * c4 + 3] = tt.w;
            }
#pragma unroll
            for (int rr = 0; rr < 4; ++rr)
#pragma unroll
                for (int cc = 0; cc < 16; ++cc)
                    acc[rr][cc] += ya[rr] * tv[cc];
        }
        float* op = out + (long)bo * (NH * NW) + (long)(hq * 64) * NW;
#pragma unroll
        for (int rr = 0; rr < 4; ++rr) {
            int h = 4 * rg + rr;
#pragma unroll
            for (int c4 = 0; c4 < 4; ++c4) {
                float4 v = make_float4(acc[rr][4 * c4], acc[rr][4 * c4 + 1],
                                       acc[rr][4 * c4 + 2], acc[rr][4 * c4 + 3]);
                *(float4*)(op + (long)h * NW + w0 + 4 * c4) = v;
            }
        }
    }
}

extern "C" void kernel_launch(void* const* d_in, const int* in_sizes, int n_in,
                              void* d_out, int out_size, void* d_ws, size_t ws_size,
                              hipStream_t stream) {
    const float* x   = (const float*)d_in[0];
    const float* wre = (const float*)d_in[1];
    const float* wim = (const float*)d_in[2];
    float* out = (float*)d_out;
    float* ws  = (float*)d_ws;

    init_tabs<<<dim3(40), dim3(256), 0, stream>>>(ws);
    fwd_kernel<<<dim3(NB * NCI), dim3(256), 0, stream>>>(x, ws);
    mix_kernel<<<dim3(1024), dim3(256), 0, stream>>>(wre, wim, ws);
    inv_kernel<<<dim3(NB * NCO * 4), dim3(256), 0, stream>>>(ws, out);
}

// Round 2
// 303.716 us; speedup vs baseline: 1.5060x; 1.5060x over previous
//
#include <hip/hip_runtime.h>

constexpr int NB = 16;
constexpr int NCI = 64;
constexpr int NCO = 64;
constexpr int NH = 256;
constexpr int NW = 256;
constexpr int NM1 = 20;
constexpr int NM2 = 20;
constexpr int NMODES = 400;

// workspace layout (float offsets)
constexpr long OFF_TWS  = 0;                                  // fwd twiddle [256][48]
constexpr long OFF_TINV = 12288;                              // Tc[20][16][12] | Ts[20][16][12]
constexpr long OFF_XL   = OFF_TINV + 7680;                    // [NB][NCI][400][2]
constexpr long OFF_OL   = OFF_XL + (long)NB*NCI*NMODES*2;     // [NB][NCO][400][2]

constexpr float TWO_PI = 6.28318530717958647692f;
constexpr float INV_N2 = 1.0f / 65536.0f;

// ---------------- table init ----------------------------------------------------
// tws[w][12*cg+q] = (q<10) ? T[w][10cg+q] : 0, where T[w][2ky]=cos(2pi ky w/256),
// T[w][2ky+1]=-sin(...).  Tc/Ts[ky][lg][q] = cky*{cos,sin}(2pi ky (8lg+1+q)/256)/65536.
__global__ void init_tabs(float* __restrict__ ws) {
    int e = blockIdx.x * 256 + threadIdx.x;
    if (e < 12288) {
        int w = e / 48, s = e % 48;
        int cg = s / 12, q = s % 12;
        float v = 0.f;
        if (q < 10) {
            int n = 10 * cg + q, ky = n >> 1, p = n & 1;
            float ang = TWO_PI * (float)((ky * w) & 255) * (1.0f / 256.0f);
            float sn, cn; sincosf(ang, &sn, &cn);
            v = p ? -sn : cn;
        }
        ws[OFF_TWS + e] = v;
    } else if (e < 19968) {
        int f = e - 12288;
        int tb = f / 3840, rr = f % 3840;
        int ky = rr / 192, g = (rr % 192) / 12, q = rr % 12;
        float v = 0.f;
        if (q < 8) {
            int w = 8 * g + 1 + q;
            float ang = TWO_PI * (float)((ky * w) & 255) * (1.0f / 256.0f);
            float sn, cn; sincosf(ang, &sn, &cn);
            float cky = (ky == 0) ? 1.0f : 2.0f;
            v = (tb == 0 ? cn : sn) * cky * INV_N2;
        }
        ws[OFF_TINV + f] = v;
    }
}

// ---------------- forward: x -> X_low (fused W-DFT then H-DFT) ------------------
// one block per (b*64+i); 256 threads; 3 blocks/CU
__launch_bounds__(256, 3)
__global__ void fwd_kernel(const float* __restrict__ x, float* __restrict__ ws) {
    __shared__ float sm[13376];
    float* cs   = sm;                 // [256][2]
    float* sXT  = sm + 512;           // [32][260] transposed x chunk   (phase 1)
    float* T2f  = sm + 512 + 8320;    // [32][48] twiddle chunk         (phase 1)
    float* sA   = sm + 512;           // [256][44] A[h][n]  (aliases sXT/T2f)
    float* sRed = sm + 512 + 11264;   // [200][8]
    const int t = threadIdx.x;
    const int r = blockIdx.x;                 // b*64+i
    const float* xr = x + (long)r * (NH * NW);
    const float* tws = ws + OFF_TWS;

    { float ang = TWO_PI * (float)t * (1.0f/256.0f); float s,c; sincosf(ang,&s,&c);
      cs[2*t] = c; cs[2*t+1] = s; }

    const int rg = t >> 2;    // [0,64): 4 h-rows each
    const int cg = t & 3;     // [0,4): 10 n-cols each (n = 10cg+q)
    float acc[4][10];
#pragma unroll
    for (int a0 = 0; a0 < 4; a0++)
#pragma unroll
        for (int a1 = 0; a1 < 10; a1++) acc[a0][a1] = 0.f;

    for (int kc = 0; kc < 8; ++kc) {
        __syncthreads();
        {   // stage twiddle chunk [32][48] = 1536 floats
            const float* src = tws + (long)kc * 1536;
            *(float4*)(T2f + 4*t) = *(const float4*)(src + 4*t);
            int u = t + 256;
            if (u < 384) *(float4*)(T2f + 4*u) = *(const float4*)(src + 4*u);
        }
        // stage x chunk transposed: sXT[w][h]
#pragma unroll
        for (int j = 0; j < 8; ++j) {
            int e = t + 256*j;
            int h = e >> 3, kq = e & 7;
            float4 g = *(const float4*)(xr + (long)h * NW + kc*32 + kq*4);
            float* d = sXT + (4*kq)*260 + h;
            d[0] = g.x; d[260] = g.y; d[520] = g.z; d[780] = g.w;
        }
        __syncthreads();
#pragma unroll 2
        for (int k = 0; k < 32; ++k) {
            float4 xv = *(const float4*)(sXT + k*260 + 4*rg);
            const float* tp = T2f + k*48 + 12*cg;
            float4 t0 = *(const float4*)(tp);
            float4 t1 = *(const float4*)(tp + 4);
            float4 t2 = *(const float4*)(tp + 8);
            float xa[4] = {xv.x, xv.y, xv.z, xv.w};
            float tv[10] = {t0.x,t0.y,t0.z,t0.w, t1.x,t1.y,t1.z,t1.w, t2.x,t2.y};
#pragma unroll
            for (int rr = 0; rr < 4; ++rr)
#pragma unroll
                for (int q = 0; q < 10; ++q)
                    acc[rr][q] += xa[rr] * tv[q];
        }
    }
    __syncthreads();   // everyone done reading sXT before sA overwrites it
#pragma unroll
    for (int rr = 0; rr < 4; ++rr)
#pragma unroll
        for (int q = 0; q < 10; ++q)
            sA[(4*rg + rr)*44 + 10*cg + q] = acc[rr][q];
    __syncthreads();

    // phase 2: X_low[kx,ky] = sum_h A[h][.] * e^{-2pi i kx h/256}
    float a2[8];
#pragma unroll
    for (int q = 0; q < 8; q++) a2[q] = 0.f;
    if (t < 200) {
        int p = t % 100, sh = t / 100;
        int kxg = p / 10, kyg = p % 10;
        int kx0 = 2 * kxg;
        for (int it = 0; it < 128; ++it) {
            int h = 128 * sh + it;
            float4 a = *(const float4*)(sA + h*44 + 4*kyg); // re0,im0,re1,im1
            int i0 = (kx0 * h) & 255;
            int i1 = (i0 + h) & 255;
            float c0 = cs[2*i0], s0 = cs[2*i0+1];
            float c1 = cs[2*i1], s1 = cs[2*i1+1];
            a2[0] += a.x*c0 + a.y*s0;  a2[1] += a.y*c0 - a.x*s0;
            a2[2] += a.z*c0 + a.w*s0;  a2[3] += a.w*c0 - a.z*s0;
            a2[4] += a.x*c1 + a.y*s1;  a2[5] += a.y*c1 - a.x*s1;
            a2[6] += a.z*c1 + a.w*s1;  a2[7] += a.w*c1 - a.z*s1;
        }
#pragma unroll
        for (int q = 0; q < 8; q++) sRed[t*8 + q] = a2[q];
    }
    __syncthreads();
    if (t < 100) {
        int kxg = t / 10, kyg = t % 10;
        float* xl = ws + OFF_XL + (long)r * (NMODES * 2);
#pragma unroll
        for (int kxi = 0; kxi < 2; kxi++)
#pragma unroll
            for (int kyi = 0; kyi < 2; kyi++) {
                int q = kxi*4 + kyi*2;
                float re = sRed[t*8 + q]     + sRed[(t+100)*8 + q];
                float im = sRed[t*8 + q + 1] + sRed[(t+100)*8 + q + 1];
                int m = (2*kxg + kxi) * NM2 + (2*kyg + kyi);
                xl[2*m]     = re;
                xl[2*m + 1] = im;
            }
    }
}

// ---------------- channel mix: OL[b,o,m] = sum_i X[b,i,m]*W[i,o,m] --------------
__launch_bounds__(256, 4)
__global__ void mix_kernel(const float* __restrict__ wre, const float* __restrict__ wim,
                           float* __restrict__ ws) {
    __shared__ float sw[200];
    __shared__ float sx[800];
    const int t = threadIdx.x;
    const int blk = blockIdx.x;
    const int o  = blk >> 4;
    const int mq = (blk >> 2) & 3;
    const int bq = blk & 3;
    const int m0 = mq * 100;
    const float* XL = ws + OFF_XL;
    float acc[2][2];
    acc[0][0] = acc[0][1] = acc[1][0] = acc[1][1] = 0.f;
    for (int i = 0; i < NCI; ++i) {
        __syncthreads();
        if (t < 100)      sw[t] = wre[(long)(i * NCO + o) * NMODES + m0 + t];
        else if (t < 200) sw[t] = wim[(long)(i * NCO + o) * NMODES + m0 + (t - 100)];
#pragma unroll
        for (int j = 0; j < 4; ++j) {
            int u = t + 256 * j;
            if (u < 800) {
                int bl = u / 200, q = u % 200;
                int b = 4 * bq + bl;
                sx[u] = XL[((long)(b * NCI + i) * NMODES + m0) * 2 + q];
            }
        }
        __syncthreads();
#pragma unroll
        for (int j = 0; j < 2; ++j) {
            int v = t + 256 * j;
            if (v < 400) {
                int bl = v / 100, ml = v % 100;
                float xr = sx[bl*200 + 2*ml], xi = sx[bl*200 + 2*ml + 1];
                float wr = sw[ml], wi = sw[100 + ml];
                acc[j][0] += xr * wr - xi * wi;
                acc[j][1] += xr * wi + xi * wr;
            }
        }
    }
    float* OL = ws + OFF_OL;
#pragma unroll
    for (int j = 0; j < 2; ++j) {
        int v = t + 256 * j;
        if (v < 400) {
            int bl = v / 100, ml = v % 100;
            int b = 4 * bq + bl;
            long a = ((long)(b * NCO + o) * NMODES + m0 + ml) * 2;
            OL[a]     = acc[j][0];
            OL[a + 1] = acc[j][1];
        }
    }
}

// ---------------- inverse: OL -> out (fused H-iDFT then symmetric W-iDFT) -------
// grid 4096: (bo, hq); 256 threads; 3 blocks/CU
__launch_bounds__(256, 3)
__global__ void inv_kernel(const float* __restrict__ ws, float* __restrict__ out) {
    __shared__ float sm2[11712];
    float* sOL = sm2;            // 800
    float* cs  = sm2 + 800;      // 512
    float* sYr = sm2 + 1312;     // [20][68]
    float* sYi = sm2 + 2672;     // [20][68]
    float* sTc = sm2 + 4032;     // [20][16][12]
    float* sTs = sm2 + 7872;     // [20][16][12]
    const int t = threadIdx.x;
    const int blk = blockIdx.x;
    const int bo = blk >> 2;     // b*64+o
    const int hq = blk & 3;

    { float ang = TWO_PI * (float)t * (1.0f/256.0f); float s,c; sincosf(ang,&s,&c);
      cs[2*t] = c; cs[2*t+1] = s; }
    {
        const float* OL = ws + OFF_OL + (long)bo * (NMODES * 2);
#pragma unroll
        for (int j = 0; j < 4; ++j) {
            int u = t + 256 * j;
            if (u < 800) sOL[u] = OL[u];
        }
        const float* TI = ws + OFF_TINV;
#pragma unroll
        for (int j = 0; j < 8; ++j) {
            int u = t + 256 * j;
            if (u < 1920) *(float4*)(sTc + 4*u) = *(const float4*)(TI + 4*u);
        }
    }
    __syncthreads();

    // phase 1: Yc[ky][h] = sum_kx OL[kx][ky] e^{+2pi i kx h/256}
    {
        int hloc = t >> 2, kyq = t & 3;
        int h = hq * 64 + hloc;
        float a[5][2];
#pragma unroll
        for (int kk = 0; kk < 5; kk++) { a[kk][0] = 0.f; a[kk][1] = 0.f; }
        for (int kx = 0; kx < NM1; ++kx) {
            int idx = (kx * h) & 255;
            float c = cs[2*idx], s = cs[2*idx+1];
#pragma unroll
            for (int kk = 0; kk < 5; ++kk) {
                int ky = kyq * 5 + kk;
                float pr = sOL[2*(kx*NM2 + ky)], pi = sOL[2*(kx*NM2 + ky) + 1];
                a[kk][0] += pr * c - pi * s;
                a[kk][1] += pr * s + pi * c;
            }
        }
#pragma unroll
        for (int kk = 0; kk < 5; ++kk) {
            int ky = kyq * 5 + kk;
            sYr[ky*68 + hloc] = a[kk][0];
            sYi[ky*68 + hloc] = a[kk][1];
        }
    }
    __syncthreads();

    // phase 2: U = sum_ky Yr*Tc, V = sum_ky Yi*Ts; out[w]=U-V, out[256-w]=U+V
    {
        const int lg = t & 15;      // leader group: w = 8lg+1 .. 8lg+8
        const int hg = t >> 4;      // 4 h-rows: h = hq*64 + 4hg + rr
        float U[4][8], V[4][8];
#pragma unroll
        for (int rr = 0; rr < 4; rr++)
#pragma unroll
            for (int c = 0; c < 8; c++) { U[rr][c] = 0.f; V[rr][c] = 0.f; }
        for (int ky = 0; ky < 20; ++ky) {
            float4 yr = *(const float4*)(sYr + ky*68 + 4*hg);
            float4 yi = *(const float4*)(sYi + ky*68 + 4*hg);
            const float* tcp = sTc + ky*192 + lg*12;
            const float* tsp = sTs + ky*192 + lg*12;
            float4 c0 = *(const float4*)(tcp), c1 = *(const float4*)(tcp + 4);
            float4 s0 = *(const float4*)(tsp), s1 = *(const float4*)(tsp + 4);
            float ya[4] = {yr.x, yr.y, yr.z, yr.w};
            float yb[4] = {yi.x, yi.y, yi.z, yi.w};
            float tc[8] = {c0.x,c0.y,c0.z,c0.w, c1.x,c1.y,c1.z,c1.w};
            float ts[8] = {s0.x,s0.y,s0.z,s0.w, s1.x,s1.y,s1.z,s1.w};
#pragma unroll
            for (int rr = 0; rr < 4; ++rr)
#pragma unroll
                for (int c = 0; c < 8; ++c) {
                    U[rr][c] += ya[rr] * tc[c];
                    V[rr][c] += yb[rr] * ts[c];
                }
        }
        float* orow0 = out + (long)bo * (NH*NW) + (long)(hq*64 + 4*hg) * NW;
#pragma unroll
        for (int rr = 0; rr < 4; ++rr) {
            float* orow = orow0 + (long)rr * NW;
            float L[8], F[8];
#pragma unroll
            for (int c = 0; c < 8; ++c) { L[c] = U[rr][c] - V[rr][c]; F[c] = U[rr][c] + V[rr][c]; }
            int wl = 8*lg + 1;
            orow[wl] = L[0];
            *(float2*)(orow + wl + 1) = make_float2(L[1], L[2]);
            *(float4*)(orow + wl + 3) = make_float4(L[3], L[4], L[5], L[6]);
            orow[wl + 7] = L[7];
            *(float4*)(orow + 252 - 8*lg) = make_float4(F[3], F[2], F[1], F[0]);
            *(float4*)(orow + 248 - 8*lg) = make_float4(F[7], F[6], F[5], F[4]);
        }
    }
    // w = 0 column: out[h][0] = sum_ky cky*Yr[ky][h]/N2   (sin term = 0)
    if (t < 64) {
        float sum = 0.f;
        for (int ky = 0; ky < 20; ++ky)
            sum += sYr[ky*68 + t] * ((ky == 0) ? 1.0f : 2.0f);
        out[(long)bo * (NH*NW) + (long)(hq*64 + t) * NW] = sum * INV_N2;
    }
}

extern "C" void kernel_launch(void* const* d_in, const int* in_sizes, int n_in,
                              void* d_out, int out_size, void* d_ws, size_t ws_size,
                              hipStream_t stream) {
    const float* x   = (const float*)d_in[0];
    const float* wre = (const float*)d_in[1];
    const float* wim = (const float*)d_in[2];
    float* out = (float*)d_out;
    float* ws  = (float*)d_ws;

    init_tabs<<<dim3(78), dim3(256), 0, stream>>>(ws);
    fwd_kernel<<<dim3(NB * NCI), dim3(256), 0, stream>>>(x, ws);
    mix_kernel<<<dim3(1024), dim3(256), 0, stream>>>(wre, wim, ws);
    inv_kernel<<<dim3(NB * NCO * 4), dim3(256), 0, stream>>>(ws, out);
}